// Round 1
// baseline (562.738 us; speedup 1.0000x reference)
//
#include <hip/hip_runtime.h>
#include <hip/hip_bf16.h>

#define B_ 1024
#define L_ 50
#define K_ 20
#define D_ 64
#define N_ITEMS 100000
#define ALPHA 0.2f

typedef __bf16 bf16x8 __attribute__((ext_vector_type(8)));
typedef float f32x4 __attribute__((ext_vector_type(4)));

// round-to-nearest-even f32 -> bf16 bits
__device__ __forceinline__ unsigned short f2b(float f) {
    union { float f; unsigned int u; } x; x.f = f;
    unsigned int r = (x.u + 0x7FFFu + ((x.u >> 16) & 1u)) >> 16;
    return (unsigned short)r;
}

// ---------------- kernel 1: item_table fp32 -> bf16 ----------------
__global__ void convert_kernel(const float* __restrict__ in,
                               unsigned short* __restrict__ out, int n4) {
    int i = blockIdx.x * blockDim.x + threadIdx.x;
    if (i < n4) {
        float4 v = ((const float4*)in)[i];
        ushort4 o;
        o.x = f2b(v.x); o.y = f2b(v.y); o.z = f2b(v.z); o.w = f2b(v.w);
        ((ushort4*)out)[i] = o;
    }
}

// ---------------- kernel 2: per-batch memory recurrence ----------------
// one wave (64 lanes) per batch element; lane = d. mem[k] in registers.
__global__ __launch_bounds__(64) void recur_kernel(
    const float* __restrict__ item_table, const float* __restrict__ user_table,
    const float* __restrict__ memory_init, const int* __restrict__ user_id,
    const int* __restrict__ seq, const int* __restrict__ seq_len,
    unsigned short* __restrict__ pu_out) {
    const int b = blockIdx.x;
    const int lane = threadIdx.x;
    const int T = seq_len[b];
    float mem[K_];
#pragma unroll
    for (int k = 0; k < K_; ++k)
        mem[k] = memory_init[(b * K_ + k) * D_ + lane];

    const int* sq = seq + b * L_;
    float e_next = item_table[(size_t)sq[0] * D_ + lane];  // prefetch t=0

    for (int t = 0; t < T; ++t) {
        float e = e_next;
        int tn = (t + 1 < L_) ? (t + 1) : t;               // always-safe prefetch
        e_next = item_table[(size_t)sq[tn] * D_ + lane];

        float w[K_];
#pragma unroll
        for (int k = 0; k < K_; ++k) w[k] = mem[k] * e;
#pragma unroll
        for (int off = 32; off > 0; off >>= 1) {
#pragma unroll
            for (int k = 0; k < K_; ++k) w[k] += __shfl_xor(w[k], off, 64);
        }
        // softmax over k
        float mx = w[0];
#pragma unroll
        for (int k = 1; k < K_; ++k) mx = fmaxf(mx, w[k]);
        float s = 0.0f;
#pragma unroll
        for (int k = 0; k < K_; ++k) { w[k] = __expf(w[k] - mx); s += w[k]; }
        float inv = 1.0f / s;
        float er = 1.0f / (1.0f + __expf(-e));     // sigmoid(e)
        float t2 = __expf(2.0f * e);
        float ad = (t2 - 1.0f) / (t2 + 1.0f);      // tanh(e)
#pragma unroll
        for (int k = 0; k < K_; ++k) {
            float z = w[k] * inv;
            mem[k] = mem[k] * (1.0f - z * er) + z * ad;
        }
    }

    // final attention with the LAST item in seq (always index L-1)
    float last = item_table[(size_t)sq[L_ - 1] * D_ + lane];
    float w[K_];
#pragma unroll
    for (int k = 0; k < K_; ++k) w[k] = mem[k] * last;
#pragma unroll
    for (int off = 32; off > 0; off >>= 1) {
#pragma unroll
        for (int k = 0; k < K_; ++k) w[k] += __shfl_xor(w[k], off, 64);
    }
    float mx = w[0];
#pragma unroll
    for (int k = 1; k < K_; ++k) mx = fmaxf(mx, w[k]);
    float s = 0.0f;
#pragma unroll
    for (int k = 0; k < K_; ++k) { w[k] = __expf(w[k] - mx); s += w[k]; }
    float inv = 1.0f / s;
    float p = 0.0f;
#pragma unroll
    for (int k = 0; k < K_; ++k) p += (w[k] * inv) * mem[k];

    float pu = user_table[(size_t)user_id[b] * D_ + lane] + ALPHA * p;
    pu_out[b * D_ + lane] = f2b(pu);
}

// ---------------- kernel 3: scores = pu @ item_table^T (bf16 MFMA) ----------
// block = 256 threads = 4 waves stacked along M; block tile 256M x 64N.
// per wave: 64M x 64N via 16 subtiles of 16x16, K=64 = 2 MFMAs each.
// A (pu, M x K row-major) and B (item, N x K row-major) frags loaded
// identically: lane holds row[lane&15], k = (lane>>4)*8 + j (+32 for half 1).
// D: row = (lane>>4)*4 + reg, col = lane&15.   [verified layouts: m89/m97]
__global__ __launch_bounds__(256) void gemm_kernel(
    const unsigned short* __restrict__ itemb,  // N_ITEMS x 64 bf16
    const unsigned short* __restrict__ pub,    // 1024 x 64 bf16
    float* __restrict__ out) {
    const int lane = threadIdx.x & 63;
    const int wv = threadIdx.x >> 6;
    const int r = lane & 15;
    const int q = lane >> 4;
    const int m0 = blockIdx.x * 256 + wv * 64;
    const int n0 = blockIdx.y * 64;

    bf16x8 a[4][2], bb[4][2];
#pragma unroll
    for (int sm = 0; sm < 4; ++sm) {
        const unsigned short* p = pub + (m0 + sm * 16 + r) * 64 + q * 8;
        a[sm][0] = *(const bf16x8*)(p);
        a[sm][1] = *(const bf16x8*)(p + 32);
    }
    bf16x8 zf;
#pragma unroll
    for (int i = 0; i < 8; ++i) zf[i] = (__bf16)0.0f;
#pragma unroll
    for (int sn = 0; sn < 4; ++sn) {
        int n = n0 + sn * 16 + r;
        if (n < N_ITEMS) {
            const unsigned short* p = itemb + (size_t)n * 64 + q * 8;
            bb[sn][0] = *(const bf16x8*)(p);
            bb[sn][1] = *(const bf16x8*)(p + 32);
        } else {
            bb[sn][0] = zf;
            bb[sn][1] = zf;
        }
    }

    f32x4 acc[4][4];
#pragma unroll
    for (int sm = 0; sm < 4; ++sm)
#pragma unroll
        for (int sn = 0; sn < 4; ++sn) {
            f32x4 c = {0.0f, 0.0f, 0.0f, 0.0f};
            c = __builtin_amdgcn_mfma_f32_16x16x32_bf16(a[sm][0], bb[sn][0], c, 0, 0, 0);
            c = __builtin_amdgcn_mfma_f32_16x16x32_bf16(a[sm][1], bb[sn][1], c, 0, 0, 0);
            acc[sm][sn] = c;
        }

#pragma unroll
    for (int sm = 0; sm < 4; ++sm)
#pragma unroll
        for (int sn = 0; sn < 4; ++sn) {
            int n = n0 + sn * 16 + r;
            if (n < N_ITEMS) {
                int mbase = m0 + sm * 16 + q * 4;
#pragma unroll
                for (int rr = 0; rr < 4; ++rr)
                    out[(size_t)(mbase + rr) * N_ITEMS + n] = acc[sm][sn][rr];
            }
        }
}

extern "C" void kernel_launch(void* const* d_in, const int* in_sizes, int n_in,
                              void* d_out, int out_size, void* d_ws, size_t ws_size,
                              hipStream_t stream) {
    const float* item_table  = (const float*)d_in[0];
    const float* user_table  = (const float*)d_in[1];
    const float* memory_init = (const float*)d_in[2];
    const int*   user_id     = (const int*)d_in[3];
    const int*   seq         = (const int*)d_in[4];
    const int*   seq_len     = (const int*)d_in[5];
    float* out = (float*)d_out;

    unsigned short* item_bf16 = (unsigned short*)d_ws;            // 12.8 MB
    unsigned short* pu_bf16   = item_bf16 + (size_t)N_ITEMS * D_; // 128 KB

    int n4 = N_ITEMS * D_ / 4;
    convert_kernel<<<dim3((n4 + 255) / 256), dim3(256), 0, stream>>>(
        item_table, item_bf16, n4);
    recur_kernel<<<dim3(B_), dim3(64), 0, stream>>>(
        item_table, user_table, memory_init, user_id, seq, seq_len, pu_bf16);
    gemm_kernel<<<dim3(4, (N_ITEMS + 63) / 64), dim3(256), 0, stream>>>(
        item_bf16, pu_bf16, out);
}